// Round 11
// baseline (191.519 us; speedup 1.0000x reference)
//
#include <hip/hip_runtime.h>
#include <math.h>

#define CDIM 256
#define NSEQ 4096
#define HWDIM 64
#define PPIX 4356   // 66*66 padded pixels

typedef unsigned short u16;
typedef __attribute__((ext_vector_type(8))) short bf16x8;
typedef __attribute__((ext_vector_type(4))) float f32x4;
typedef __attribute__((ext_vector_type(16))) float f32x16;

__device__ __forceinline__ u16 f2bf(float f) {
    unsigned u = __float_as_uint(f);
    unsigned r = (u + 0x7FFFu + ((u >> 16) & 1u)) >> 16;   // RN-even
    return (u16)r;
}

// async global->LDS, 16B per lane; LDS dest = wave-uniform base + lane*16
__device__ __forceinline__ void gload_lds16(const u16* g, u16* l) {
    __builtin_amdgcn_global_load_lds(
        (const __attribute__((address_space(1))) unsigned int*)g,
        (__attribute__((address_space(3))) unsigned int*)l, 16, 0, 0);
}

// ---------------------------------------------------------------------------
// pad+transpose: ref fp32 NCHW -> padded bf16 [b][pp][c], pp=(y+1)*66+(x+1)
// ---------------------------------------------------------------------------
__global__ __launch_bounds__(256)
void pad_transpose_kernel(const float* __restrict__ x, u16* __restrict__ padded)
{
    __shared__ float lds[64 * 65];
    const int tid = threadIdx.x;
    const int y = blockIdx.x, c0 = blockIdx.y << 6, b = blockIdx.z;
    #pragma unroll
    for (int i = 0; i < 16; ++i) {
        int f = tid + (i << 8);
        int c = f >> 6, xx = f & 63;
        lds[c * 65 + xx] = x[(((size_t)(b * CDIM + c0 + c)) * HWDIM + y) * HWDIM + xx];
    }
    __syncthreads();
    #pragma unroll
    for (int i = 0; i < 2; ++i) {
        int f = tid + (i << 8);
        int xx = f >> 3, c8 = f & 7;
        union { u16 h[8]; float4 v; } pk;
        #pragma unroll
        for (int j = 0; j < 8; ++j) pk.h[j] = f2bf(lds[(c8 * 8 + j) * 65 + xx]);
        *(float4*)&padded[((size_t)b * PPIX + (y + 1) * 66 + (xx + 1)) * CDIM + c0 + (c8 << 3)] = pk.v;
    }
}

// ---------------------------------------------------------------------------
// weight prepack: w fp32 [co][ci][3][3] -> wk bf16 [kyx][co][ci]
// ---------------------------------------------------------------------------
__global__ __launch_bounds__(256)
void w_prepack_kernel(const float* __restrict__ w, u16* __restrict__ wk)
{
    int t = (blockIdx.x << 8) + threadIdx.x;
    const float* wp = w + (size_t)t * 9;
    #pragma unroll
    for (int j = 0; j < 9; ++j) wk[j * 65536 + t] = f2bf(wp[j]);
}

// ---------------------------------------------------------------------------
// conv3x3+ReLU as 9 offset-GEMMs over the padded image. bf16 MFMA, fp32 acc.
// OA=true : D[n][co] -> Vn[b][co][n]   (conv2)
// OA=false: D[co][n] -> XT[b][n][co]   (conv1)
// ---------------------------------------------------------------------------
template <bool OA>
__global__ __launch_bounds__(256)
void conv_mfma_kernel(const u16* __restrict__ padded, const u16* __restrict__ wk,
                      u16* __restrict__ out)
{
    __shared__ alignas(16) u16 Xs[64 * 64];
    __shared__ alignas(16) u16 Ws[128 * 64];

    const int tid = threadIdx.x;
    const int lane = tid & 63, wv = tid >> 6;
    const int lr = lane & 15, lg = lane >> 4;
    const int cb = blockIdx.x << 7;
    const int y0 = blockIdx.y;
    const int b = blockIdx.z;

    constexpr int MF = OA ? 4 : 2;
    constexpr int NF = OA ? 2 : 4;
    f32x4 acc[MF][NF] = {};

    for (int t = 0; t < 36; ++t) {
        const int kyx = t >> 2, cib = (t & 3) << 6;
        const int ky = kyx / 3, kx = kyx - ky * 3;
        __syncthreads();
        #pragma unroll
        for (int i = 0; i < 2; ++i) {
            int f = tid + (i << 8);
            int r = f >> 3, c8 = f & 7;
            int pp = (y0 + ky) * 66 + r + kx;
            float4 v = *(const float4*)&padded[((size_t)b * PPIX + pp) * CDIM + cib + (c8 << 3)];
            *(float4*)&Xs[(r << 6) + ((c8 << 3) ^ ((r & 7) << 3))] = v;
        }
        #pragma unroll
        for (int i = 0; i < 4; ++i) {
            int f = tid + (i << 8);
            int r = f >> 3, c8 = f & 7;
            float4 v = *(const float4*)&wk[((size_t)kyx << 16) + (size_t)(cb + r) * 256 + cib + (c8 << 3)];
            *(float4*)&Ws[(r << 6) + ((c8 << 3) ^ ((r & 7) << 3))] = v;
        }
        __syncthreads();
        #pragma unroll
        for (int kk = 0; kk < 2; ++kk) {
            const int ca = ((kk << 5) + (lg << 3)) ^ ((lr & 7) << 3);
            if constexpr (OA) {
                bf16x8 a[4], bb[2];
                #pragma unroll
                for (int mf = 0; mf < 4; ++mf)
                    a[mf] = *(const bf16x8*)&Xs[((mf * 16 + lr) << 6) + ca];
                #pragma unroll
                for (int nf = 0; nf < 2; ++nf)
                    bb[nf] = *(const bf16x8*)&Ws[((wv * 32 + nf * 16 + lr) << 6) + ca];
                #pragma unroll
                for (int mf = 0; mf < 4; ++mf)
                    #pragma unroll
                    for (int nf = 0; nf < 2; ++nf)
                        acc[mf][nf] = __builtin_amdgcn_mfma_f32_16x16x32_bf16(a[mf], bb[nf], acc[mf][nf], 0, 0, 0);
            } else {
                bf16x8 a[2], bb[4];
                #pragma unroll
                for (int mf = 0; mf < 2; ++mf)
                    a[mf] = *(const bf16x8*)&Ws[((wv * 32 + mf * 16 + lr) << 6) + ca];
                #pragma unroll
                for (int nf = 0; nf < 4; ++nf)
                    bb[nf] = *(const bf16x8*)&Xs[((nf * 16 + lr) << 6) + ca];
                #pragma unroll
                for (int mf = 0; mf < 2; ++mf)
                    #pragma unroll
                    for (int nf = 0; nf < 4; ++nf)
                        acc[mf][nf] = __builtin_amdgcn_mfma_f32_16x16x32_bf16(a[mf], bb[nf], acc[mf][nf], 0, 0, 0);
            }
        }
    }

    const int m0 = y0 << 6;
    if constexpr (OA) {
        #pragma unroll
        for (int mf = 0; mf < 4; ++mf)
            #pragma unroll
            for (int nf = 0; nf < 2; ++nf) {
                int nb = m0 + mf * 16 + lg * 4;
                int co = cb + wv * 32 + nf * 16 + lr;
                union { u16 h[4]; uint2 v; } pk;
                #pragma unroll
                for (int j = 0; j < 4; ++j) pk.h[j] = f2bf(fmaxf(acc[mf][nf][j], 0.f));
                *(uint2*)&out[((size_t)(b * CDIM + co)) * NSEQ + nb] = pk.v;
            }
    } else {
        #pragma unroll
        for (int mf = 0; mf < 2; ++mf)
            #pragma unroll
            for (int nf = 0; nf < 4; ++nf) {
                int cob = cb + wv * 32 + mf * 16 + lg * 4;
                int n = m0 + nf * 16 + lr;
                union { u16 h[4]; uint2 v; } pk;
                #pragma unroll
                for (int j = 0; j < 4; ++j) pk.h[j] = f2bf(fmaxf(acc[mf][nf][j], 0.f));
                *(uint2*)&out[((size_t)(b * NSEQ + n)) * CDIM + cob] = pk.v;
            }
    }
}

// ---------------------------------------------------------------------------
// rownorm: rn2[row] = sum_c XT[row][c]^2 ; bmax[block] = max of its 4 rows.
// NO atomics (G12): per-block max written to bmax, reduced by maxred_kernel.
// ---------------------------------------------------------------------------
__global__ __launch_bounds__(256)
void rownorm_kernel(const u16* __restrict__ XT, float* __restrict__ rn2,
                    float* __restrict__ bmax)
{
    __shared__ float wmax[4];
    const int tid = threadIdx.x;
    const int lane = tid & 63, wv = tid >> 6;
    const int row = (blockIdx.x << 2) + wv;          // 0..16383
    const u16* xp = &XT[(size_t)row * CDIM + (lane << 2)];
    uint2 v = *(const uint2*)xp;
    float s = 0.f;
    #pragma unroll
    for (int j = 0; j < 4; ++j) {
        unsigned hu = (j & 1) ? ((&v.x)[j >> 1] >> 16) : ((&v.x)[j >> 1] & 0xFFFFu);
        float x = __uint_as_float(hu << 16);
        s += x * x;
    }
    #pragma unroll
    for (int off = 1; off < 64; off <<= 1) s += __shfl_xor(s, off);
    if (lane == 0) {
        rn2[row] = s;
        wmax[wv] = s;
    }
    __syncthreads();
    if (tid == 0)
        bmax[blockIdx.x] = fmaxf(fmaxf(wmax[0], wmax[1]), fmaxf(wmax[2], wmax[3]));
}

// ---------------------------------------------------------------------------
// maxred: maxrn2[b] = max over the batch's 1024 block-maxes. 4 blocks.
// ---------------------------------------------------------------------------
__global__ __launch_bounds__(256)
void maxred_kernel(const float* __restrict__ bmax, float* __restrict__ maxrn2)
{
    __shared__ float wred[4];
    const int tid = threadIdx.x;
    const int lane = tid & 63, wv = tid >> 6;
    const int b = blockIdx.x;
    float m = 0.f;
    #pragma unroll
    for (int i = 0; i < 4; ++i)
        m = fmaxf(m, bmax[(b << 10) + (i << 8) + tid]);
    #pragma unroll
    for (int off = 1; off < 64; off <<= 1) m = fmaxf(m, __shfl_xor(m, off));
    if (lane == 0) wred[wv] = m;
    __syncthreads();
    if (tid == 0)
        maxrn2[b] = fmaxf(fmaxf(wred[0], wred[1]), fmaxf(wred[2], wred[3]));
}

// ---------------------------------------------------------------------------
// Flash attention partials, 2-way key split, 32x32x16 MFMA, static-bound
// softmax (R9), IN-REGISTER P (T12: v_cvt_pk_bf16_f32 + v_permlane32_swap):
// wave (qt,kh) computes QK for its 32 queries x its 32-key half, converts p
// to PV B-fragments entirely in registers, then PV over all 256 c for its
// own keys. No P LDS round-trip, ONE barrier per chunk, waves decoupled
// (static mq offset is shared -> kh halves are independent, partials add).
// Epilogue: kh=0 waves park O in dead K/V LDS; kh=1 waves add + store.
// ---------------------------------------------------------------------------
#define M_TILE 128
#define NC 64
#define NCHUNKS 32

// LDS map (u16 units): K dbuf 2x16384, V dbuf 2x16384 = 128 KB total
#define KS_OFF 0
#define VS_OFF 32768

__device__ __forceinline__ void stage_chunk(const u16* __restrict__ XT, const u16* __restrict__ Vn,
                                            u16* Kb, u16* Vb, int b, int n0, int wv, int lane)
{
    #pragma unroll
    for (int i = 0; i < 4; ++i) {
        int f = ((i << 3) + wv) << 6;          // wave-uniform 16B-unit base
        int fl = f + lane;
        int r = fl >> 5;                        // key row 0..63
        int gsw = (fl & 31) ^ (r & 15);         // 4-bit pre-swizzle
        gload_lds16(&XT[(size_t)(b * NSEQ + n0 + r) * CDIM + (gsw << 3)], Kb + (f << 3));
    }
    #pragma unroll
    for (int i = 0; i < 4; ++i) {
        int f = ((i << 3) + wv) << 6;
        int fl = f + lane;
        int r = fl >> 3;                        // channel row 0..255
        int gsw = (fl & 7) ^ (r & 7);           // 3-bit pre-swizzle
        gload_lds16(&Vn[(size_t)(b * CDIM + r) * NSEQ + n0 + (gsw << 3)], Vb + (f << 3));
    }
}

__global__ __launch_bounds__(512, 2)
void attn_part_kernel(const u16* __restrict__ XT, const u16* __restrict__ Vn,
                      const float* __restrict__ rn2, const float* __restrict__ maxrn2,
                      float* __restrict__ o0, u16* __restrict__ o1,
                      float* __restrict__ lsum)
{
    __shared__ alignas(16) u16 smem[65536];     // 128 KB (K/V dbuf; f32 O overlay at end)

    const int tid = threadIdx.x;
    const int lane = tid & 63;
    const int wv = tid >> 6;                    // 0..7
    const int l31 = lane & 31;
    const int hi = lane >> 5;
    const int bh = blockIdx.x;                  // b*2+h
    const int b = bh >> 1, h = bh & 1;
    const int m0 = blockIdx.y * M_TILE;
    const int nbase = h * (NSEQ / 2);

    const int qt = wv & 3;                      // q-tile (32 q), wave-owned
    const int kh = wv >> 2;                     // key half (32 of 64 chunk keys)
    const int qa = qt * 32 + l31;               // block-local query

    // static softmax offset: m_ub(q) = ||x_q|| * max_n ||x_n||  (>= all logits)
    const float mq = sqrtf(rn2[(size_t)b * NSEQ + m0 + qa]) * sqrtf(maxrn2[b]);

    // Q as B-operand frags in registers: k = kstep*16 + hi*8 + j
    bf16x8 qreg[16];
    {
        const u16* qrow = &XT[(size_t)(b * NSEQ + m0 + qa) * CDIM + (hi << 3)];
        #pragma unroll
        for (int ks = 0; ks < 16; ++ks)
            qreg[ks] = *(const bf16x8*)(qrow + (ks << 4));
    }

    f32x16 o[8] = {};                           // O^T[c][q]: 8 c-tiles x own keys
    float lrun = 0.f;

    stage_chunk(XT, Vn, smem + KS_OFF, smem + VS_OFF, b, nbase, wv, lane);
    __syncthreads();

    int cur = 0;
    for (int ci = 0; ci < NCHUNKS; ++ci) {
        if (ci + 1 < NCHUNKS)
            stage_chunk(XT, Vn, smem + KS_OFF + (cur ^ 1) * 16384,
                        smem + VS_OFF + (cur ^ 1) * 16384,
                        b, nbase + (ci + 1) * NC, wv, lane);

        const u16* Kc = smem + KS_OFF + cur * 16384;
        const u16* Vc = smem + VS_OFF + cur * 16384;

        // ---- QK^T: s = D[key][q] over own 32-key half ----
        f32x16 s = {};
        {
            const int krow = kh * 32 + l31;     // A row = key (lane&31)
            const u16* kbase = &Kc[krow << 8];
            const int ksw = krow & 15;
            #pragma unroll
            for (int ks = 0; ks < 16; ++ks) {
                bf16x8 ka = *(const bf16x8*)&kbase[(((ks << 1) + hi) ^ ksw) << 3];
                s = __builtin_amdgcn_mfma_f32_32x32x16_bf16(ka, qreg[ks], s, 0, 0, 0);
            }
        }

        // ---- p = exp(s - m_ub), own-half denominator ----
        float p[16];
        float ps = 0.f;
        #pragma unroll
        for (int r = 0; r < 16; ++r) { p[r] = __expf(s[r] - mq); ps += p[r]; }
        ps += __shfl_xor(ps, 32);
        lrun += ps;

        // ---- in-register P -> PV B-frags (cvt_pk + permlane32_swap) ----
        // D rows held: (reg&3)+8*(reg>>2)+4*hi. w[j]=pack(p[2j],p[2j+1]).
        // swap(w0,w2),(w1,w3) -> frag ks=0 dwords {0,1}{2,3}{4,5}{6,7} per hi;
        // swap(w4,w6),(w5,w7) -> frag ks=1.
        unsigned w[8];
        #pragma unroll
        for (int j = 0; j < 8; ++j)
            asm("v_cvt_pk_bf16_f32 %0, %1, %2" : "=v"(w[j]) : "v"(p[2 * j]), "v"(p[2 * j + 1]));
        asm volatile("v_permlane32_swap_b32 %0, %1" : "+v"(w[0]), "+v"(w[2]));
        asm volatile("v_permlane32_swap_b32 %0, %1" : "+v"(w[1]), "+v"(w[3]));
        asm volatile("v_permlane32_swap_b32 %0, %1" : "+v"(w[4]), "+v"(w[6]));
        asm volatile("v_permlane32_swap_b32 %0, %1" : "+v"(w[5]), "+v"(w[7]));
        union { unsigned u[4]; bf16x8 v; } pb0, pb1;
        pb0.u[0] = w[0]; pb0.u[1] = w[1]; pb0.u[2] = w[2]; pb0.u[3] = w[3];
        pb1.u[0] = w[4]; pb1.u[1] = w[5]; pb1.u[2] = w[6]; pb1.u[3] = w[7];

        // ---- PV: O^T[c][q] += V^T[c][own keys] P[own keys][q] ----
        {
            #pragma unroll
            for (int cs = 0; cs < 8; ++cs) {
                const int crow = cs * 32 + l31;
                const int csw = (crow & 7);
                const u16* vbase = &Vc[crow << 6];
                bf16x8 va0 = *(const bf16x8*)&vbase[(((kh << 2) + 0 + hi) ^ csw) << 3];
                bf16x8 va1 = *(const bf16x8*)&vbase[(((kh << 2) + 2 + hi) ^ csw) << 3];
                o[cs] = __builtin_amdgcn_mfma_f32_32x32x16_bf16(va0, pb0.v, o[cs], 0, 0, 0);
                o[cs] = __builtin_amdgcn_mfma_f32_32x32x16_bf16(va1, pb1.v, o[cs], 0, 0, 0);
            }
        }

        __syncthreads();    // single barrier: staging drained, buffers protected
        cur ^= 1;
    }

    // ---- l per query, per (h,kh) stream (merge layout unchanged) ----
    if (lane < 32)
        lsum[(size_t)(((h * 2 + kh) * 4 + b)) * NSEQ + m0 + qa] = lrun;

    // ---- cross-kh O sum via LDS (K/V regions dead now) ----
    float* oq = (float*)smem + qt * 8192;       // [256c][32q] f32 per q-tile
    if (kh == 0) {
        #pragma unroll
        for (int cs = 0; cs < 8; ++cs)
            #pragma unroll
            for (int reg = 0; reg < 16; ++reg) {
                int rloc = (reg & 3) + ((reg >> 2) << 3) + (hi << 2);
                oq[((cs << 5) + rloc) * 32 + l31] = o[cs][reg];
            }
    }
    __syncthreads();
    if (kh == 1) {
        #pragma unroll
        for (int cs = 0; cs < 8; ++cs)
            #pragma unroll
            for (int reg = 0; reg < 16; ++reg) {
                int rloc = (reg & 3) + ((reg >> 2) << 3) + (hi << 2);
                float val = o[cs][reg] + oq[((cs << 5) + rloc) * 32 + l31];
                int c = (cs << 5) + rloc;
                int q = m0 + qt * 32 + l31;
                size_t oi = ((size_t)(b * CDIM + c)) * NSEQ + q;
                if (h == 0) o0[oi] = val;
                else        o1[oi] = f2bf(val);
            }
    }
}

// ---------------------------------------------------------------------------
// merge: out[i] = g * (O0[i] + O1[i]) / (l00+l01+l10+l11) + ref[i]
// (all streams share the same static m(q) -> weights cancel; in-place safe)
// ---------------------------------------------------------------------------
__global__ __launch_bounds__(256)
void merge_kernel(float* __restrict__ out, const u16* __restrict__ o1,
                  const float* __restrict__ lsum, const float* __restrict__ ref,
                  const float* __restrict__ gptr)
{
    const int f = (blockIdx.x << 8) + threadIdx.x;   // per float4 of out
    const int n4 = f & 1023;                          // n0 = n4*4
    const int c = (f >> 10) & 255;
    const int b = f >> 18;
    const float g = gptr[0];

    float4 p0 = ((const float4*)out)[f];
    uint2 q1 = *(const uint2*)&o1[((size_t)(b * CDIM + c)) * NSEQ + (n4 << 2)];
    float4 rf = ((const float4*)ref)[f];

    float res[4];
    #pragma unroll
    for (int j = 0; j < 4; ++j) {
        int row = (n4 << 2) + j;
        float l = lsum[(size_t)(0 * 4 + b) * NSEQ + row]
                + lsum[(size_t)(1 * 4 + b) * NSEQ + row]
                + lsum[(size_t)(2 * 4 + b) * NSEQ + row]
                + lsum[(size_t)(3 * 4 + b) * NSEQ + row];
        float rl = 1.0f / l;
        float v0 = ((const float*)&p0)[j];
        unsigned hu = ((j & 1) ? ((&q1.x)[j >> 1] >> 16) : ((&q1.x)[j >> 1] & 0xFFFFu));
        float v1 = __uint_as_float(hu << 16);
        float a = (v0 + v1) * rl;
        res[j] = g * a + ((const float*)&rf)[j];
    }
    ((float4*)out)[f] = *(float4*)res;
}

// ---------------------------------------------------------------------------
extern "C" void kernel_launch(void* const* d_in, const int* in_sizes, int n_in,
                              void* d_out, int out_size, void* d_ws, size_t ws_size,
                              hipStream_t stream)
{
    // dict order: inputs, ref, w1, w2, gamma (dead conv on `inputs` skipped)
    const float* ref = (const float*)d_in[1];
    const float* w1  = (const float*)d_in[2];
    const float* w2  = (const float*)d_in[3];
    const float* gma = (const float*)d_in[4];
    float* out = (float*)d_out;

    u16* XT     = (u16*)d_ws;                          // [B][N][C] bf16 (Q=K)  8.39 MB
    u16* Vn     = XT + (size_t)4 * NSEQ * CDIM;        // [B][C][N] bf16 (V)    8.39 MB
    u16* padded = Vn + (size_t)4 * NSEQ * CDIM;        // [B][4356][256] bf16   8.9 MB (dead after convs)
    u16* wk1    = padded + (size_t)4 * PPIX * CDIM;    // 1.18 MB (dead after convs)
    u16* wk2    = wk1 + (size_t)9 * 65536;             // 1.18 MB (dead after convs)
    // attn-phase reuse of dead regions:
    u16*   o1     = padded;                            // [B][C][N] bf16 partial (8.39 MB)
    float* lsum   = (float*)wk1;                       // [4][B][N] f32 (0.26 MB)
    float* rn2    = (float*)wk2;                       // [B][N] f32 (64 KB)
    float* bmax   = rn2 + 16384;                       // [4096] f32 (16 KB)
    float* maxrn2 = bmax + 4096;                       // [4] f32

    hipMemsetAsync(padded, 0, (size_t)4 * PPIX * CDIM * sizeof(u16), stream);
    pad_transpose_kernel<<<dim3(64, 4, 4), 256, 0, stream>>>(ref, padded);
    w_prepack_kernel<<<dim3(256), 256, 0, stream>>>(w1, wk1);
    w_prepack_kernel<<<dim3(256), 256, 0, stream>>>(w2, wk2);

    dim3 cgrid(2, 64, 4);
    conv_mfma_kernel<false><<<cgrid, 256, 0, stream>>>(padded, wk1, XT);  // -> XT
    conv_mfma_kernel<true ><<<cgrid, 256, 0, stream>>>(padded, wk2, Vn);  // -> Vn

    rownorm_kernel<<<dim3(4096), 256, 0, stream>>>(XT, rn2, bmax);        // no atomics
    maxred_kernel<<<dim3(4), 256, 0, stream>>>(bmax, maxrn2);

    attn_part_kernel<<<dim3(8, NSEQ / M_TILE), 512, 0, stream>>>(XT, Vn, rn2, maxrn2, out, o1, lsum);
    merge_kernel<<<dim3((4 * CDIM * NSEQ / 4) / 256), 256, 0, stream>>>(out, o1, lsum, ref, gma);
}

// Round 12
// 168.822 us; speedup vs baseline: 1.1344x; 1.1344x over previous
//
#include <hip/hip_runtime.h>
#include <math.h>

#define CDIM 256
#define NSEQ 4096
#define HWDIM 64
#define PPIX 4356   // 66*66 padded pixels

typedef unsigned short u16;
typedef __attribute__((ext_vector_type(8))) short bf16x8;
typedef __attribute__((ext_vector_type(4))) float f32x4;
typedef __attribute__((ext_vector_type(16))) float f32x16;

__device__ __forceinline__ u16 f2bf(float f) {
    unsigned u = __float_as_uint(f);
    unsigned r = (u + 0x7FFFu + ((u >> 16) & 1u)) >> 16;   // RN-even
    return (u16)r;
}

// async global->LDS, 16B per lane; LDS dest = wave-uniform base + lane*16
__device__ __forceinline__ void gload_lds16(const u16* g, u16* l) {
    __builtin_amdgcn_global_load_lds(
        (const __attribute__((address_space(1))) unsigned int*)g,
        (__attribute__((address_space(3))) unsigned int*)l, 16, 0, 0);
}

// ---------------------------------------------------------------------------
// pad+transpose: ref fp32 NCHW -> padded bf16 [b][pp][c], pp=(y+1)*66+(x+1)
// ---------------------------------------------------------------------------
__global__ __launch_bounds__(256)
void pad_transpose_kernel(const float* __restrict__ x, u16* __restrict__ padded)
{
    __shared__ float lds[64 * 65];
    const int tid = threadIdx.x;
    const int y = blockIdx.x, c0 = blockIdx.y << 6, b = blockIdx.z;
    #pragma unroll
    for (int i = 0; i < 16; ++i) {
        int f = tid + (i << 8);
        int c = f >> 6, xx = f & 63;
        lds[c * 65 + xx] = x[(((size_t)(b * CDIM + c0 + c)) * HWDIM + y) * HWDIM + xx];
    }
    __syncthreads();
    #pragma unroll
    for (int i = 0; i < 2; ++i) {
        int f = tid + (i << 8);
        int xx = f >> 3, c8 = f & 7;
        union { u16 h[8]; float4 v; } pk;
        #pragma unroll
        for (int j = 0; j < 8; ++j) pk.h[j] = f2bf(lds[(c8 * 8 + j) * 65 + xx]);
        *(float4*)&padded[((size_t)b * PPIX + (y + 1) * 66 + (xx + 1)) * CDIM + c0 + (c8 << 3)] = pk.v;
    }
}

// ---------------------------------------------------------------------------
// weight prepack: w fp32 [co][ci][3][3] -> wk bf16 [kyx][co][ci]
// ---------------------------------------------------------------------------
__global__ __launch_bounds__(256)
void w_prepack_kernel(const float* __restrict__ w, u16* __restrict__ wk)
{
    int t = (blockIdx.x << 8) + threadIdx.x;
    const float* wp = w + (size_t)t * 9;
    #pragma unroll
    for (int j = 0; j < 9; ++j) wk[j * 65536 + t] = f2bf(wp[j]);
}

// ---------------------------------------------------------------------------
// conv3x3+ReLU as 9 offset-GEMMs, now double-buffered via global_load_lds
// (T21: pre-swizzled GLOBAL source, linear LDS dest; reads unchanged).
// One barrier per K-step. LDS: X dbuf 2x8KB + W dbuf 2x16KB = 48 KB.
// OA=true : D[n][co] -> Vn[b][co][n]   (conv2)
// OA=false: D[co][n] -> XT[b][n][co]   (conv1)
// ---------------------------------------------------------------------------
__device__ __forceinline__ void conv_stage(const u16* __restrict__ padded,
                                           const u16* __restrict__ wk,
                                           u16* Xb, u16* Wb,
                                           int b, int y0, int cb, int t,
                                           int wv, int lane)
{
    const int kyx = t >> 2, cib = (t & 3) << 6;
    const int ky = kyx / 3, kx = kyx - ky * 3;
    #pragma unroll
    for (int i = 0; i < 2; ++i) {
        int f = ((i << 2) + wv) << 6;          // wave-uniform 16B-unit base
        int fl = f + lane;
        int r = fl >> 3;                        // x-pixel 0..63
        int gsw = (fl & 7) ^ (r & 7);           // 3-bit pre-swizzle
        gload_lds16(&padded[((size_t)b * PPIX + (y0 + ky) * 66 + r + kx) * CDIM + cib + (gsw << 3)],
                    Xb + (f << 3));
    }
    #pragma unroll
    for (int i = 0; i < 4; ++i) {
        int f = ((i << 2) + wv) << 6;
        int fl = f + lane;
        int r = fl >> 3;                        // co 0..127
        int gsw = (fl & 7) ^ (r & 7);
        gload_lds16(&wk[((size_t)kyx << 16) + (size_t)(cb + r) * 256 + cib + (gsw << 3)],
                    Wb + (f << 3));
    }
}

template <bool OA>
__global__ __launch_bounds__(256)
void conv_mfma_kernel(const u16* __restrict__ padded, const u16* __restrict__ wk,
                      u16* __restrict__ out)
{
    __shared__ alignas(16) u16 smem[24576];    // [X0 4096][X1 4096][W0 8192][W1 8192]

    const int tid = threadIdx.x;
    const int lane = tid & 63, wv = tid >> 6;
    const int lr = lane & 15, lg = lane >> 4;
    const int cb = blockIdx.x << 7;
    const int y0 = blockIdx.y;
    const int b = blockIdx.z;

    constexpr int MF = OA ? 4 : 2;
    constexpr int NF = OA ? 2 : 4;
    f32x4 acc[MF][NF] = {};

    conv_stage(padded, wk, smem, smem + 8192, b, y0, cb, 0, wv, lane);
    __syncthreads();

    int cur = 0;
    for (int t = 0; t < 36; ++t) {
        if (t + 1 < 36)
            conv_stage(padded, wk, smem + (cur ^ 1) * 4096,
                       smem + 8192 + (cur ^ 1) * 8192, b, y0, cb, t + 1, wv, lane);

        const u16* Xs = smem + cur * 4096;
        const u16* Ws = smem + 8192 + cur * 8192;

        #pragma unroll
        for (int kk = 0; kk < 2; ++kk) {
            const int ca = ((kk << 5) + (lg << 3)) ^ ((lr & 7) << 3);
            if constexpr (OA) {
                bf16x8 a[4], bb[2];
                #pragma unroll
                for (int mf = 0; mf < 4; ++mf)
                    a[mf] = *(const bf16x8*)&Xs[((mf * 16 + lr) << 6) + ca];
                #pragma unroll
                for (int nf = 0; nf < 2; ++nf)
                    bb[nf] = *(const bf16x8*)&Ws[((wv * 32 + nf * 16 + lr) << 6) + ca];
                #pragma unroll
                for (int mf = 0; mf < 4; ++mf)
                    #pragma unroll
                    for (int nf = 0; nf < 2; ++nf)
                        acc[mf][nf] = __builtin_amdgcn_mfma_f32_16x16x32_bf16(a[mf], bb[nf], acc[mf][nf], 0, 0, 0);
            } else {
                bf16x8 a[2], bb[4];
                #pragma unroll
                for (int mf = 0; mf < 2; ++mf)
                    a[mf] = *(const bf16x8*)&Ws[((wv * 32 + mf * 16 + lr) << 6) + ca];
                #pragma unroll
                for (int nf = 0; nf < 4; ++nf)
                    bb[nf] = *(const bf16x8*)&Xs[((nf * 16 + lr) << 6) + ca];
                #pragma unroll
                for (int mf = 0; mf < 2; ++mf)
                    #pragma unroll
                    for (int nf = 0; nf < 4; ++nf)
                        acc[mf][nf] = __builtin_amdgcn_mfma_f32_16x16x32_bf16(a[mf], bb[nf], acc[mf][nf], 0, 0, 0);
            }
        }
        __syncthreads();   // next buffer staged (vmcnt drained); this buffer reusable
        cur ^= 1;
    }

    const int m0 = y0 << 6;
    if constexpr (OA) {
        #pragma unroll
        for (int mf = 0; mf < 4; ++mf)
            #pragma unroll
            for (int nf = 0; nf < 2; ++nf) {
                int nb = m0 + mf * 16 + lg * 4;
                int co = cb + wv * 32 + nf * 16 + lr;
                union { u16 h[4]; uint2 v; } pk;
                #pragma unroll
                for (int j = 0; j < 4; ++j) pk.h[j] = f2bf(fmaxf(acc[mf][nf][j], 0.f));
                *(uint2*)&out[((size_t)(b * CDIM + co)) * NSEQ + nb] = pk.v;
            }
    } else {
        #pragma unroll
        for (int mf = 0; mf < 2; ++mf)
            #pragma unroll
            for (int nf = 0; nf < 4; ++nf) {
                int cob = cb + wv * 32 + mf * 16 + lg * 4;
                int n = m0 + nf * 16 + lr;
                union { u16 h[4]; uint2 v; } pk;
                #pragma unroll
                for (int j = 0; j < 4; ++j) pk.h[j] = f2bf(fmaxf(acc[mf][nf][j], 0.f));
                *(uint2*)&out[((size_t)(b * NSEQ + n)) * CDIM + cob] = pk.v;
            }
    }
}

// ---------------------------------------------------------------------------
// rownorm: rn2[row] = sum_c XT[row][c]^2 ; bmax[block] = max of its 4 rows.
// ---------------------------------------------------------------------------
__global__ __launch_bounds__(256)
void rownorm_kernel(const u16* __restrict__ XT, float* __restrict__ rn2,
                    float* __restrict__ bmax)
{
    __shared__ float wmax[4];
    const int tid = threadIdx.x;
    const int lane = tid & 63, wv = tid >> 6;
    const int row = (blockIdx.x << 2) + wv;          // 0..16383
    const u16* xp = &XT[(size_t)row * CDIM + (lane << 2)];
    uint2 v = *(const uint2*)xp;
    float s = 0.f;
    #pragma unroll
    for (int j = 0; j < 4; ++j) {
        unsigned hu = (j & 1) ? ((&v.x)[j >> 1] >> 16) : ((&v.x)[j >> 1] & 0xFFFFu);
        float x = __uint_as_float(hu << 16);
        s += x * x;
    }
    #pragma unroll
    for (int off = 1; off < 64; off <<= 1) s += __shfl_xor(s, off);
    if (lane == 0) {
        rn2[row] = s;
        wmax[wv] = s;
    }
    __syncthreads();
    if (tid == 0)
        bmax[blockIdx.x] = fmaxf(fmaxf(wmax[0], wmax[1]), fmaxf(wmax[2], wmax[3]));
}

// ---------------------------------------------------------------------------
// maxred: maxrn2[b] = max over the batch's 1024 block-maxes. 4 blocks.
// ---------------------------------------------------------------------------
__global__ __launch_bounds__(256)
void maxred_kernel(const float* __restrict__ bmax, float* __restrict__ maxrn2)
{
    __shared__ float wred[4];
    const int tid = threadIdx.x;
    const int lane = tid & 63, wv = tid >> 6;
    const int b = blockIdx.x;
    float m = 0.f;
    #pragma unroll
    for (int i = 0; i < 4; ++i)
        m = fmaxf(m, bmax[(b << 10) + (i << 8) + tid]);
    #pragma unroll
    for (int off = 1; off < 64; off <<= 1) m = fmaxf(m, __shfl_xor(m, off));
    if (lane == 0) wred[wv] = m;
    __syncthreads();
    if (tid == 0)
        maxrn2[b] = fmaxf(fmaxf(wred[0], wred[1]), fmaxf(wred[2], wred[3]));
}

// ---------------------------------------------------------------------------
// Flash attention partials (R10 structure, proven 90us) + dual QK accumulator
// chains (halve dependent-MFMA latency) + s_setprio around MFMA clusters.
// Static-bound softmax (Cauchy-Schwarz m_ub), 2-way key split, 32x32x16 MFMA.
// ---------------------------------------------------------------------------
#define M_TILE 128
#define NC 64
#define NCHUNKS 32

// LDS map (u16 units)
#define KS_OFF 0        // 2 x [64 key][256 c]  (4-bit row XOR swizzle)
#define VS_OFF 32768    // 2 x [256 c][64 n]    (3-bit row XOR swizzle)
#define P_OFF  65536    // [128 q][64 key]      (3-bit row XOR swizzle)

__device__ __forceinline__ void stage_chunk(const u16* __restrict__ XT, const u16* __restrict__ Vn,
                                            u16* Kb, u16* Vb, int b, int n0, int wv, int lane)
{
    #pragma unroll
    for (int i = 0; i < 4; ++i) {
        int f = ((i << 3) + wv) << 6;          // wave-uniform 16B-unit base
        int fl = f + lane;
        int r = fl >> 5;                        // key row 0..63
        int gsw = (fl & 31) ^ (r & 15);         // 4-bit pre-swizzle
        gload_lds16(&XT[(size_t)(b * NSEQ + n0 + r) * CDIM + (gsw << 3)], Kb + (f << 3));
    }
    #pragma unroll
    for (int i = 0; i < 4; ++i) {
        int f = ((i << 3) + wv) << 6;
        int fl = f + lane;
        int r = fl >> 3;                        // channel row 0..255
        int gsw = (fl & 7) ^ (r & 7);           // 3-bit pre-swizzle
        gload_lds16(&Vn[(size_t)(b * CDIM + r) * NSEQ + n0 + (gsw << 3)], Vb + (f << 3));
    }
}

__global__ __launch_bounds__(512, 2)
void attn_part_kernel(const u16* __restrict__ XT, const u16* __restrict__ Vn,
                      const float* __restrict__ rn2, const float* __restrict__ maxrn2,
                      float* __restrict__ o0, u16* __restrict__ o1,
                      float* __restrict__ lsum)
{
    __shared__ alignas(16) u16 smem[73728];     // 147.5 KB
    u16* Ps = smem + P_OFF;

    const int tid = threadIdx.x;
    const int lane = tid & 63;
    const int wv = tid >> 6;                    // 0..7
    const int l31 = lane & 31;
    const int hi = lane >> 5;
    const int bh = blockIdx.x;                  // b*2+h
    const int b = bh >> 1, h = bh & 1;
    const int m0 = blockIdx.y * M_TILE;
    const int nbase = h * (NSEQ / 2);

    // QK roles
    const int qt = wv & 3;                      // q-tile (32 q)
    const int kh = wv >> 2;                     // key half (32 keys)
    const int qa = qt * 32 + l31;               // block-local query (QK phase)
    // PV roles
    const int qsel = wv & 1;                    // q-tiles qsel*2 .. +1
    const int csel = wv >> 1;                   // c-tiles csel*2 .. +1

    // static softmax offset: m_ub(q) = ||x_q|| * max_n ||x_n||  (>= all logits)
    const float mq = sqrtf(rn2[(size_t)b * NSEQ + m0 + qa]) * sqrtf(maxrn2[b]);

    // Q as B-operand frags in registers: k = kstep*16 + hi*8 + j
    bf16x8 qreg[16];
    {
        const u16* qrow = &XT[(size_t)(b * NSEQ + m0 + qa) * CDIM + (hi << 3)];
        #pragma unroll
        for (int ks = 0; ks < 16; ++ks)
            qreg[ks] = *(const bf16x8*)(qrow + (ks << 4));
    }

    f32x16 o[2][2] = {};                        // [qi][ci] O^T[c][q] unnormalized
    float lrun = 0.f;                           // own (h,kh) partial denominator

    stage_chunk(XT, Vn, smem + KS_OFF, smem + VS_OFF, b, nbase, wv, lane);
    __syncthreads();

    int cur = 0;
    for (int ci = 0; ci < NCHUNKS; ++ci) {
        if (ci + 1 < NCHUNKS)
            stage_chunk(XT, Vn, smem + KS_OFF + (cur ^ 1) * 16384,
                        smem + VS_OFF + (cur ^ 1) * 16384,
                        b, nbase + (ci + 1) * NC, wv, lane);

        const u16* Kc = smem + KS_OFF + cur * 16384;
        const u16* Vc = smem + VS_OFF + cur * 16384;

        // ---- QK^T: dual accumulator chains (even/odd ks) ----
        f32x16 s0 = {}, s1 = {};
        {
            const int krow = kh * 32 + l31;     // A row = lane&31
            const u16* kbase = &Kc[krow << 8];
            const int ksw = krow & 15;
            __builtin_amdgcn_s_setprio(1);
            #pragma unroll
            for (int ks = 0; ks < 16; ks += 2) {
                bf16x8 ka0 = *(const bf16x8*)&kbase[((((ks + 0) << 1) + hi) ^ ksw) << 3];
                bf16x8 ka1 = *(const bf16x8*)&kbase[((((ks + 1) << 1) + hi) ^ ksw) << 3];
                s0 = __builtin_amdgcn_mfma_f32_32x32x16_bf16(ka0, qreg[ks], s0, 0, 0, 0);
                s1 = __builtin_amdgcn_mfma_f32_32x32x16_bf16(ka1, qreg[ks + 1], s1, 0, 0, 0);
            }
            __builtin_amdgcn_s_setprio(0);
        }
        f32x16 s = s0 + s1;

        // ---- p = exp(s - m_ub): branchless, no max tree, no exchange ----
        float p[16];
        float ps = 0.f;
        #pragma unroll
        for (int r = 0; r < 16; ++r) { p[r] = __expf(s[r] - mq); ps += p[r]; }
        ps += __shfl_xor(ps, 32);
        lrun += ps;

        // ---- P -> LDS [q][key^swz], packed b64 writes ----
        {
            const int swz = qa & 7;
            #pragma unroll
            for (int r4 = 0; r4 < 4; ++r4) {
                union { u16 h4[4]; uint2 v; } pk;
                pk.h4[0] = f2bf(p[r4 * 4 + 0]); pk.h4[1] = f2bf(p[r4 * 4 + 1]);
                pk.h4[2] = f2bf(p[r4 * 4 + 2]); pk.h4[3] = f2bf(p[r4 * 4 + 3]);
                int g = (kh << 2) + r4;
                *(uint2*)&Ps[(qa << 6) + (((g ^ swz) << 3) | (hi << 2))] = pk.v;
            }
        }
        __syncthreads();                        // B2: P visible; staging drained

        // ---- PV: O^T[c][q] += V^T[c][n] P[n][q] ----
        {
            const int q0 = ((qsel << 1) + 0) * 32 + l31;
            const int q1 = ((qsel << 1) + 1) * 32 + l31;
            const int c0 = ((csel << 1) + 0) * 32 + l31;
            const int c1 = ((csel << 1) + 1) * 32 + l31;
            __builtin_amdgcn_s_setprio(1);
            #pragma unroll
            for (int ks = 0; ks < 4; ++ks) {
                const int gp = (ks << 1) + hi;  // n-group 0..7
                bf16x8 pb0 = *(const bf16x8*)&Ps[(q0 << 6) + ((gp ^ (q0 & 7)) << 3)];
                bf16x8 pb1 = *(const bf16x8*)&Ps[(q1 << 6) + ((gp ^ (q1 & 7)) << 3)];
                bf16x8 va0 = *(const bf16x8*)&Vc[(c0 << 6) + ((gp ^ (c0 & 7)) << 3)];
                bf16x8 va1 = *(const bf16x8*)&Vc[(c1 << 6) + ((gp ^ (c1 & 7)) << 3)];
                o[0][0] = __builtin_amdgcn_mfma_f32_32x32x16_bf16(va0, pb0, o[0][0], 0, 0, 0);
                o[0][1] = __builtin_amdgcn_mfma_f32_32x32x16_bf16(va1, pb0, o[0][1], 0, 0, 0);
                o[1][0] = __builtin_amdgcn_mfma_f32_32x32x16_bf16(va0, pb1, o[1][0], 0, 0, 0);
                o[1][1] = __builtin_amdgcn_mfma_f32_32x32x16_bf16(va1, pb1, o[1][1], 0, 0, 0);
            }
            __builtin_amdgcn_s_setprio(0);
        }

        __syncthreads();                        // B3: PV reads done, buffers free
        cur ^= 1;
    }

    // ---- l per query, per (h,kh) stream ----
    if (lane < 32)
        lsum[(size_t)(((h * 2 + kh) * 4 + b)) * NSEQ + m0 + qa] = lrun;

    // ---- partial store: D[c][q] frags -> [b][c][m] directly ----
    #pragma unroll
    for (int qi = 0; qi < 2; ++qi) {
        const int q = m0 + ((qsel << 1) + qi) * 32 + l31;
        #pragma unroll
        for (int cj = 0; cj < 2; ++cj) {
            #pragma unroll
            for (int reg = 0; reg < 16; ++reg) {
                int c = ((csel << 1) + cj) * 32 + (reg & 3) + ((reg >> 2) << 3) + (hi << 2);
                size_t oi = ((size_t)(b * CDIM + c)) * NSEQ + q;
                if (h == 0) o0[oi] = o[qi][cj][reg];
                else        o1[oi] = f2bf(o[qi][cj][reg]);
            }
        }
    }
}

// ---------------------------------------------------------------------------
// merge: out[i] = g * (O0[i] + O1[i]) / (l00+l01+l10+l11) + ref[i]
// (all streams share the same static m(q) -> weights cancel; in-place safe)
// ---------------------------------------------------------------------------
__global__ __launch_bounds__(256)
void merge_kernel(float* __restrict__ out, const u16* __restrict__ o1,
                  const float* __restrict__ lsum, const float* __restrict__ ref,
                  const float* __restrict__ gptr)
{
    const int f = (blockIdx.x << 8) + threadIdx.x;   // per float4 of out
    const int n4 = f & 1023;                          // n0 = n4*4
    const int c = (f >> 10) & 255;
    const int b = f >> 18;
    const float g = gptr[0];

    float4 p0 = ((const float4*)out)[f];
    uint2 q1 = *(const uint2*)&o1[((size_t)(b * CDIM + c)) * NSEQ + (n4 << 2)];
    float4 rf = ((const float4*)ref)[f];

    float res[4];
    #pragma unroll
    for (int j = 0; j < 4; ++j) {
        int row = (n4 << 2) + j;
        float l = lsum[(size_t)(0 * 4 + b) * NSEQ + row]
                + lsum[(size_t)(1 * 4 + b) * NSEQ + row]
                + lsum[(size_t)(2 * 4 + b) * NSEQ + row]
                + lsum[(size_t)(3 * 4 + b) * NSEQ + row];
        float rl = 1.0f / l;
        float v0 = ((const float*)&p0)[j];
        unsigned hu = ((j & 1) ? ((&q1.x)[j >> 1] >> 16) : ((&q1.x)[j >> 1] & 0xFFFFu));
        float v1 = __uint_as_float(hu << 16);
        float a = (v0 + v1) * rl;
        res[j] = g * a + ((const float*)&rf)[j];
    }
    ((float4*)out)[f] = *(float4*)res;
}

// ---------------------------------------------------------------------------
extern "C" void kernel_launch(void* const* d_in, const int* in_sizes, int n_in,
                              void* d_out, int out_size, void* d_ws, size_t ws_size,
                              hipStream_t stream)
{
    // dict order: inputs, ref, w1, w2, gamma (dead conv on `inputs` skipped)
    const float* ref = (const float*)d_in[1];
    const float* w1  = (const float*)d_in[2];
    const float* w2  = (const float*)d_in[3];
    const float* gma = (const float*)d_in[4];
    float* out = (float*)d_out;

    u16* XT     = (u16*)d_ws;                          // [B][N][C] bf16 (Q=K)  8.39 MB
    u16* Vn     = XT + (size_t)4 * NSEQ * CDIM;        // [B][C][N] bf16 (V)    8.39 MB
    u16* padded = Vn + (size_t)4 * NSEQ * CDIM;        // [B][4356][256] bf16   8.9 MB (dead after convs)
    u16* wk1    = padded + (size_t)4 * PPIX * CDIM;    // 1.18 MB (dead after convs)
    u16* wk2    = wk1 + (size_t)9 * 65536;             // 1.18 MB (dead after convs)
    // attn-phase reuse of dead regions:
    u16*   o1     = padded;                            // [B][C][N] bf16 partial (8.39 MB)
    float* lsum   = (float*)wk1;                       // [4][B][N] f32 (0.26 MB)
    float* rn2    = (float*)wk2;                       // [B][N] f32 (64 KB)
    float* bmax   = rn2 + 16384;                       // [4096] f32 (16 KB)
    float* maxrn2 = bmax + 4096;                       // [4] f32

    hipMemsetAsync(padded, 0, (size_t)4 * PPIX * CDIM * sizeof(u16), stream);
    pad_transpose_kernel<<<dim3(64, 4, 4), 256, 0, stream>>>(ref, padded);
    w_prepack_kernel<<<dim3(256), 256, 0, stream>>>(w1, wk1);
    w_prepack_kernel<<<dim3(256), 256, 0, stream>>>(w2, wk2);

    dim3 cgrid(2, 64, 4);
    conv_mfma_kernel<false><<<cgrid, 256, 0, stream>>>(padded, wk1, XT);  // -> XT
    conv_mfma_kernel<true ><<<cgrid, 256, 0, stream>>>(padded, wk2, Vn);  // -> Vn

    rownorm_kernel<<<dim3(4096), 256, 0, stream>>>(XT, rn2, bmax);        // no atomics
    maxred_kernel<<<dim3(4), 256, 0, stream>>>(bmax, maxrn2);

    attn_part_kernel<<<dim3(8, NSEQ / M_TILE), 512, 0, stream>>>(XT, Vn, rn2, maxrn2, out, o1, lsum);
    merge_kernel<<<dim3((4 * CDIM * NSEQ / 4) / 256), 256, 0, stream>>>(out, o1, lsum, ref, gma);
}